// Round 7
// baseline (10192.338 us; speedup 1.0000x reference)
//
#include <hip/hip_runtime.h>

#define NWG     256
#define TPB     256
#define NL0     128          // WGs [0,128) = layer0, [128,256) = layer1
#define T_STEPS 1024
#define HD      1024
#define DIN     256
#define K0      1280         // DIN + HD
#define K1      2048         // HD + HD
#define K0P     1288         // padded LDS row stride (shorts)
#define K1P     2056
#define SMEM_BYTES (32*K1P*2)   // 131,584 B (layer1 worst case)

#define HSLAB_BYTES 131072ull            // one h snapshot: 128 planes x 64 batch x 8 bf16
#define HSLAB_U64   16384
#define HIST_DEPTH  1025                 // slot(t)=(t+1)%1025 never wraps in 1024 steps
#define HIST_BYTES  (HIST_DEPTH*HSLAB_BYTES)   // 134,348,800
#define X8_BYTES    33554432ull
#define FLAGS_BYTES 32768ull             // flags[256] @0, gen0[16] @16K, gen1[16] @20K
#define NGEN        16

typedef float  f32x4  __attribute__((ext_vector_type(4)));
typedef __bf16 bf16x8 __attribute__((ext_vector_type(8)));
typedef unsigned long long u64;

__device__ __forceinline__ unsigned short f2bf(float f){
  union { float f; unsigned u; } a; a.f = f;
  unsigned u = a.u;
  u += 0x7fffu + ((u >> 16) & 1u);   // RNE
  return (unsigned short)(u >> 16);
}
__device__ __forceinline__ float sigmf(float x){ return 1.0f/(1.0f + __expf(-x)); }
__device__ __forceinline__ float tanhf_fast(float x){ return 2.0f*sigmf(2.0f*x) - 1.0f; }

// coherent (MALL-level, cross-XCD) accessors — per-access, no L2 invalidation
__device__ __forceinline__ u64 ld64c(const u64* p){
  return __hip_atomic_load(p, __ATOMIC_RELAXED, __HIP_MEMORY_SCOPE_AGENT);
}
__device__ __forceinline__ void st16c(unsigned short* p, unsigned short v){
  __hip_atomic_store(p, v, __ATOMIC_RELAXED, __HIP_MEMORY_SCOPE_AGENT);
}
__device__ __forceinline__ unsigned ldflag(const unsigned* p){
  return __hip_atomic_load(p, __ATOMIC_RELAXED, __HIP_MEMORY_SCOPE_AGENT);
}
__device__ __forceinline__ void stflag(unsigned* p, unsigned v){
  __hip_atomic_store(p, v, __ATOMIC_RELAXED, __HIP_MEMORY_SCOPE_AGENT);
}

// PLAIN=true: normal load (L2-cacheable; safe on fresh-per-step addresses —
// dispatch-start acquire invalidated XCD L2s, address written once before read).
template<bool PLAIN>
__device__ __forceinline__ int4 ldh(const u64* p){
  int4 v;
  if (PLAIN){
    v = *(const int4*)p;
  } else {
    u64 lo = ld64c(p), hi = ld64c(p + 1);
    __builtin_memcpy(&v, &lo, 8);
    __builtin_memcpy(((char*)&v) + 8, &hi, 8);
  }
  return v;
}
__device__ __forceinline__ bf16x8 b8(const int4& v){
  bf16x8 b; __builtin_memcpy(&b, &v, 16); return b;
}

// global leader barrier over all 256 WGs (tier-0 coupled path; round-6 proven)
__device__ __forceinline__ void gridbar_all(unsigned* flags, unsigned* gen,
                                            unsigned ep, int wg, int tid){
  asm volatile("s_waitcnt vmcnt(0)" ::: "memory");
  __syncthreads();
  if (wg == 0){
    if (tid > 0){
      while (ldflag(&flags[tid*16]) < ep) __builtin_amdgcn_s_sleep(2);
    }
    __syncthreads();
    if (tid < NGEN) stflag(&gen[tid*16], ep);
    __syncthreads();
  } else {
    if (tid == 0){
      stflag(&flags[wg*16], ep);
      while (ldflag(&gen[(wg & (NGEN-1))*16]) < ep) __builtin_amdgcn_s_sleep(2);
    }
    __syncthreads();
  }
}

// layer-local leader barrier over WGs [base, base+128); leader = base.
__device__ __forceinline__ void layerbar(unsigned* flags, unsigned* gen,
                                         unsigned ep, int wg, int tid, int base){
  asm volatile("s_waitcnt vmcnt(0)" ::: "memory");  // sc1 h-stores at MALL
  __syncthreads();
  if (wg == base){
    if (tid > 0 && tid < NL0){
      while (ldflag(&flags[(base + tid)*16]) < ep) __builtin_amdgcn_s_sleep(2);
    }
    __syncthreads();
    if (tid < NGEN) stflag(&gen[tid*16], ep);
    __syncthreads();
  } else {
    if (tid == 0){
      stflag(&flags[wg*16], ep);
      while (ldflag(&gen[(wg & (NGEN-1))*16]) < ep) __builtin_amdgcn_s_sleep(2);
    }
    __syncthreads();
  }
}

// x [B,T,D] fp32 -> X8 bf16 in [T][D/8][B][8]
__global__ void xpose_kernel(const float* __restrict__ x, unsigned short* __restrict__ X8){
  int idx   = blockIdx.x*256 + threadIdx.x;
  int t     = idx >> 11;
  int rem   = idx & 2047;
  int plane = rem >> 6;
  int b     = rem & 63;
  const float* src = x + ((size_t)b << 18) + (t << 8) + (plane << 3);
  unsigned short tmp[8];
  #pragma unroll
  for (int j = 0; j < 8; ++j) tmp[j] = f2bf(src[j]);
  int4 v; __builtin_memcpy(&v, tmp, 16);
  ((int4*)X8)[idx] = v;
}

// TIER 2: h0+h1 history (plain loads, decoupled). TIER 1: h0 history plain,
// h1 dbuf coherent (decoupled). TIER 0: both dbuf coherent, coupled barrier.
template<int TIER>
__global__ void __launch_bounds__(TPB, 1)
lstm_mega(const float* __restrict__ Wih0, const float* __restrict__ Whh0,
          const float* __restrict__ bih0, const float* __restrict__ bhh0,
          const float* __restrict__ Wih1, const float* __restrict__ Whh1,
          const float* __restrict__ bih1, const float* __restrict__ bhh1,
          const unsigned short* __restrict__ X8,
          unsigned* flags, unsigned* gen0, unsigned* gen1,
          u64* H0, u64* H1, int d0, int d1,
          float* __restrict__ out)
{
  extern __shared__ unsigned short Ws[];   // [32][KP]
  const int tid   = threadIdx.x;
  const int wg    = blockIdx.x;
  const int layer = (wg >= NL0);
  const int wgl   = layer ? wg - NL0 : wg;
  const int KD    = layer ? K1  : K0;
  const int dlen  = layer ? HD  : DIN;
  const int KP    = layer ? K1P : K0P;
  const int4* X4  = (const int4*)X8;

  // ---- stage this WG's 32 gate-rows (8 cols x 4 gates) into LDS (bf16) ----
  {
    const float* Wih = layer ? Wih1 : Wih0;
    const float* Whh = layer ? Whh1 : Whh0;
    for (int m = 0; m < 32; ++m){
      int gr = (m & 3)*HD + wgl*8 + (m >> 2);      // gate-major global row
      const float* ar = Wih + (size_t)gr*dlen;
      const float* br = Whh + (size_t)gr*HD;
      unsigned short* row = Ws + m*KP;
      for (int k = tid; k < KD; k += TPB)
        row[k] = f2bf(k < dlen ? ar[k] : br[k - dlen]);
    }
  }
  __syncthreads();

  const int lane  = tid & 63;
  const int wv    = tid >> 6;
  const int q     = lane >> 4;       // k-quad (A/B frags); row-quad (C/D)
  const int nn    = lane & 15;       // A-row / B-batch / C-batch
  const int batch = wv*16 + nn;

  float bias[2][4];
  {
    const float* bi = layer ? bih1 : bih0;
    const float* bh = layer ? bhh1 : bhh0;
    #pragma unroll
    for (int rt = 0; rt < 2; ++rt){
      int colr = wgl*8 + rt*4 + q;
      #pragma unroll
      for (int r = 0; r < 4; ++r)
        bias[rt][r] = bi[r*HD + colr] + bh[r*HD + colr];
    }
  }

  float cst[2] = {0.f, 0.f};
  float hv[2]  = {0.f, 0.f};

  // epilogue: gates -> c,h update -> bf16 store to slot (t+1)%wd
  auto epi = [&](int t, f32x4 s0, f32x4 s1, u64* Hw, int wd){
    unsigned short* wbase = (unsigned short*)(Hw + (size_t)((t+1) % wd)*HSLAB_U64);
    #pragma unroll
    for (int rt = 0; rt < 2; ++rt){
      f32x4 s = rt ? s1 : s0;
      float ii = sigmf(s[0] + bias[rt][0]);
      float ff = sigmf(s[1] + bias[rt][1]);
      float gg = tanhf_fast(s[2] + bias[rt][2]);
      float oo = sigmf(s[3] + bias[rt][3]);
      cst[rt] = ff*cst[rt] + ii*gg;
      hv[rt]  = oo*tanhf_fast(cst[rt]);
      st16c(wbase + (wgl*64 + batch)*8 + (rt*4 + q), f2bf(hv[rt]));
    }
  };

  if (!layer){
    // ================= layer 0: free-running =================
    for (int t = 0; t < T_STEPS; ++t){
      const int4* xb = X4 + (size_t)t*2048;
      const u64*  hb = H0 + (size_t)(t % d0)*HSLAB_U64;

      int4 xr[8];
      #pragma unroll
      for (int kb = 0; kb < 8; ++kb)
        xr[kb] = xb[(kb*4 + q)*64 + batch];

      int4 Bh[4][8];                        // all 32 h kb-planes in flight
      #pragma unroll
      for (int c = 0; c < 4; ++c)
        #pragma unroll
        for (int i = 0; i < 8; ++i)
          Bh[c][i] = ldh<(TIER >= 1)>(hb + (((c*8 + i)*4 + q)*64 + batch)*2);

      f32x4 a00={0,0,0,0}, a01={0,0,0,0}, a10={0,0,0,0}, a11={0,0,0,0};
      auto MM = [&](int kb, bf16x8 b){
        bf16x8 w0, w1;
        __builtin_memcpy(&w0, &Ws[nn*K0P + kb*32 + q*8], 16);
        __builtin_memcpy(&w1, &Ws[(16+nn)*K0P + kb*32 + q*8], 16);
        if (kb & 1){ a01 = __builtin_amdgcn_mfma_f32_16x16x32_bf16(w0,b,a01,0,0,0);
                     a11 = __builtin_amdgcn_mfma_f32_16x16x32_bf16(w1,b,a11,0,0,0); }
        else       { a00 = __builtin_amdgcn_mfma_f32_16x16x32_bf16(w0,b,a00,0,0,0);
                     a10 = __builtin_amdgcn_mfma_f32_16x16x32_bf16(w1,b,a10,0,0,0); }
      };
      #pragma unroll
      for (int kb = 0; kb < 8; ++kb) MM(kb, b8(xr[kb]));
      #pragma unroll
      for (int c = 0; c < 4; ++c)
        #pragma unroll
        for (int i = 0; i < 8; ++i) MM(8 + c*8 + i, b8(Bh[c][i]));

      epi(t, a00 + a01, a10 + a11, H0, d0);
      if (TIER > 0) layerbar(flags, gen0, (unsigned)(t+1), wg, tid, 0);
      else          gridbar_all(flags, gen0, (unsigned)(t+1), wg, tid);
    }
  } else {
    // ================= layer 1: chases L0 via gen0 progress =================
    auto stepL1 = [&](int t, bool dowait){
      const u64* hb = H1 + (size_t)(t % d1)*HSLAB_U64;       // h1(t-1)
      const u64* yb = H0 + (size_t)((t+1) % d0)*HSLAB_U64;   // y0(t)

      int4 Bh[4][8];                       // h1 first: hides behind gen0 wait
      auto LDH = [&](int c){
        #pragma unroll
        for (int i = 0; i < 8; ++i)
          Bh[c][i] = ldh<(TIER == 2)>(hb + (((c*8 + i)*4 + q)*64 + batch)*2);
      };
      LDH(0); LDH(1); LDH(2); LDH(3);

      if (dowait){
        // wave-uniform poll, no __syncthreads -> Bh loads stay in flight
        while (ldflag(&gen0[(wg & (NGEN-1))*16]) < (unsigned)(t+1))
          __builtin_amdgcn_s_sleep(1);
      }

      int4 By[4][8];
      auto LDY = [&](int c){
        #pragma unroll
        for (int i = 0; i < 8; ++i)
          By[c][i] = ldh<(TIER >= 1)>(yb + (((c*8 + i)*4 + q)*64 + batch)*2);
      };

      f32x4 a00={0,0,0,0}, a01={0,0,0,0}, a10={0,0,0,0}, a11={0,0,0,0};
      auto MM = [&](int kb, bf16x8 b){
        bf16x8 w0, w1;
        __builtin_memcpy(&w0, &Ws[nn*K1P + kb*32 + q*8], 16);
        __builtin_memcpy(&w1, &Ws[(16+nn)*K1P + kb*32 + q*8], 16);
        if (kb & 1){ a01 = __builtin_amdgcn_mfma_f32_16x16x32_bf16(w0,b,a01,0,0,0);
                     a11 = __builtin_amdgcn_mfma_f32_16x16x32_bf16(w1,b,a11,0,0,0); }
        else       { a00 = __builtin_amdgcn_mfma_f32_16x16x32_bf16(w0,b,a00,0,0,0);
                     a10 = __builtin_amdgcn_mfma_f32_16x16x32_bf16(w1,b,a10,0,0,0); }
      };

      LDY(0); LDY(1);
      #pragma unroll
      for (int i = 0; i < 8; ++i) MM(32 + i,      b8(Bh[0][i]));   // h1 c0
      LDY(2);
      #pragma unroll
      for (int i = 0; i < 8; ++i) MM(32 + 8 + i,  b8(Bh[1][i]));   // h1 c1
      LDY(3);
      #pragma unroll
      for (int c = 2; c < 4; ++c)
        #pragma unroll
        for (int i = 0; i < 8; ++i) MM(32 + c*8 + i, b8(Bh[c][i])); // h1 c2,c3
      #pragma unroll
      for (int c = 0; c < 4; ++c)
        #pragma unroll
        for (int i = 0; i < 8; ++i) MM(c*8 + i, b8(By[c][i]));      // y0

      epi(t, a00 + a01, a10 + a11, H1, d1);
    };

    if (TIER > 0){
      for (int t = 0; t < T_STEPS; ++t){
        stepL1(t, true);
        layerbar(flags, gen1, (unsigned)(t+1), wg, tid, NL0);
      }
    } else {
      for (int s = 0; s < T_STEPS; ++s){
        if (s > 0) stepL1(s-1, false);
        gridbar_all(flags, gen0, (unsigned)(s+1), wg, tid);
      }
      stepL1(T_STEPS-1, false);
    }
  }

  // out = [h0 | h1 | c0 | c1], each [B=64, H=1024] fp32
  {
    int col0 = wgl*8 + q;
    int base = layer ? 65536 : 0;
    out[base          + batch*HD + col0    ] = hv[0];
    out[base          + batch*HD + col0 + 4] = hv[1];
    out[base + 131072 + batch*HD + col0    ] = cst[0];
    out[base + 131072 + batch*HD + col0 + 4] = cst[1];
  }
}

extern "C" void kernel_launch(void* const* d_in, const int* in_sizes, int n_in,
                              void* d_out, int out_size, void* d_ws, size_t ws_size,
                              hipStream_t stream)
{
  const float* x    = (const float*)d_in[0];
  const float* Wih0 = (const float*)d_in[1];
  const float* Whh0 = (const float*)d_in[2];
  const float* bih0 = (const float*)d_in[3];
  const float* bhh0 = (const float*)d_in[4];
  const float* Wih1 = (const float*)d_in[5];
  const float* Whh1 = (const float*)d_in[6];
  const float* bih1 = (const float*)d_in[7];
  const float* bhh1 = (const float*)d_in[8];
  float* out = (float*)d_out;

  char* ws = (char*)d_ws;
  unsigned* flags = (unsigned*)ws;
  unsigned* gen0  = (unsigned*)(ws + 16384);
  unsigned* gen1  = (unsigned*)(ws + 20480);

  const size_t need2 = FLAGS_BYTES + 2*HIST_BYTES + X8_BYTES;               // ~302 MB
  const size_t need1 = FLAGS_BYTES + HIST_BYTES + 2*HSLAB_BYTES + X8_BYTES; // ~168 MB

  u64 *H0p, *H1p; unsigned short* X8p; int d0, d1, tier;
  if (ws_size >= need2){
    tier = 2; d0 = HIST_DEPTH; d1 = HIST_DEPTH;
    H0p = (u64*)(ws + FLAGS_BYTES);
    H1p = (u64*)(ws + FLAGS_BYTES + HIST_BYTES);
    X8p = (unsigned short*)(ws + FLAGS_BYTES + 2*HIST_BYTES);
  } else if (ws_size >= need1){
    tier = 1; d0 = HIST_DEPTH; d1 = 2;
    H0p = (u64*)(ws + FLAGS_BYTES);
    H1p = (u64*)(ws + FLAGS_BYTES + HIST_BYTES);
    X8p = (unsigned short*)(ws + FLAGS_BYTES + HIST_BYTES + 2*HSLAB_BYTES);
  } else {
    tier = 0; d0 = 2; d1 = 2;
    H0p = (u64*)(ws + FLAGS_BYTES);
    H1p = (u64*)(ws + FLAGS_BYTES + 2*HSLAB_BYTES);
    X8p = (unsigned short*)(ws + FLAGS_BYTES + 4*HSLAB_BYTES);
  }

  // zero flags/gen0/gen1 + slot 0 of each h buffer (initial state h(-1)=0)
  hipMemsetAsync(flags, 0, FLAGS_BYTES, stream);
  hipMemsetAsync(H0p, 0, HSLAB_BYTES, stream);
  hipMemsetAsync(H1p, 0, HSLAB_BYTES, stream);
  xpose_kernel<<<8192, 256, 0, stream>>>(x, X8p);

  void* fn = (tier == 2) ? (void*)&lstm_mega<2>
           : (tier == 1) ? (void*)&lstm_mega<1>
                         : (void*)&lstm_mega<0>;
  hipFuncSetAttribute(fn, hipFuncAttributeMaxDynamicSharedMemorySize, SMEM_BYTES);

  const unsigned short* X8c = X8p;
  void* args[] = {(void*)&Wih0,(void*)&Whh0,(void*)&bih0,(void*)&bhh0,
                  (void*)&Wih1,(void*)&Whh1,(void*)&bih1,(void*)&bhh1,
                  (void*)&X8c,(void*)&flags,(void*)&gen0,(void*)&gen1,
                  (void*)&H0p,(void*)&H1p,(void*)&d0,(void*)&d1,(void*)&out};
  hipError_t err = hipLaunchCooperativeKernel(fn, dim3(NWG), dim3(TPB),
                                              args, SMEM_BYTES, stream);
  if (err != hipSuccess){
    // Fallback: plain launch. 256 WGs x 131.6KB LDS => 1 WG/CU, grid == CU
    // count, all WGs co-resident by capacity.
    if (tier == 2)
      lstm_mega<2><<<dim3(NWG), dim3(TPB), SMEM_BYTES, stream>>>(
        Wih0,Whh0,bih0,bhh0,Wih1,Whh1,bih1,bhh1,X8c,flags,gen0,gen1,H0p,H1p,d0,d1,out);
    else if (tier == 1)
      lstm_mega<1><<<dim3(NWG), dim3(TPB), SMEM_BYTES, stream>>>(
        Wih0,Whh0,bih0,bhh0,Wih1,Whh1,bih1,bhh1,X8c,flags,gen0,gen1,H0p,H1p,d0,d1,out);
    else
      lstm_mega<0><<<dim3(NWG), dim3(TPB), SMEM_BYTES, stream>>>(
        Wih0,Whh0,bih0,bhh0,Wih1,Whh1,bih1,bhh1,X8c,flags,gen0,gen1,H0p,H1p,d0,d1,out);
  }
}

// Round 8
// 6447.704 us; speedup vs baseline: 1.5808x; 1.5808x over previous
//
#include <hip/hip_runtime.h>

#define NWG     256
#define TPB     256
#define NL0     128          // WGs [0,128) = layer0, [128,256) = layer1
#define T_STEPS 1024
#define HD      1024
#define DIN     256
#define K0      1280         // DIN + HD
#define K1      2048         // HD + HD
#define K0P     1288         // padded LDS row stride (shorts)
#define K1P     2056
#define SMEM_BYTES (32*K1P*2)   // 131,584 B (layer1 worst case)

#define HSLAB_BYTES 131072ull            // one h snapshot: 128 planes x 64 batch x 8 bf16
#define HSLAB_U64   16384
#define HIST_DEPTH  1025                 // slot(t)=(t+1)%1025 never wraps in 1024 steps
#define HIST_BYTES  (HIST_DEPTH*HSLAB_BYTES)   // 134,348,800
#define X8_BYTES    33554432ull
#define FLAGS_BYTES 32768ull
#define NGEN        16

typedef float  f32x4  __attribute__((ext_vector_type(4)));
typedef __bf16 bf16x8 __attribute__((ext_vector_type(8)));
typedef unsigned long long u64;

__device__ __forceinline__ unsigned short f2bf(float f){
  union { float f; unsigned u; } a; a.f = f;
  unsigned u = a.u;
  u += 0x7fffu + ((u >> 16) & 1u);   // RNE
  return (unsigned short)(u >> 16);
}
__device__ __forceinline__ float sigmf(float x){ return 1.0f/(1.0f + __expf(-x)); }
__device__ __forceinline__ float tanhf_fast(float x){ return 2.0f*sigmf(2.0f*x) - 1.0f; }

// coherent (MALL-level, cross-XCD) accessors — per-access, no L2 invalidation
__device__ __forceinline__ u64 ld64c(const u64* p){
  return __hip_atomic_load(p, __ATOMIC_RELAXED, __HIP_MEMORY_SCOPE_AGENT);
}
__device__ __forceinline__ void st16c(unsigned short* p, unsigned short v){
  __hip_atomic_store(p, v, __ATOMIC_RELAXED, __HIP_MEMORY_SCOPE_AGENT);
}
__device__ __forceinline__ unsigned ldflag(const unsigned* p){
  return __hip_atomic_load(p, __ATOMIC_RELAXED, __HIP_MEMORY_SCOPE_AGENT);
}
__device__ __forceinline__ void stflag(unsigned* p, unsigned v){
  __hip_atomic_store(p, v, __ATOMIC_RELAXED, __HIP_MEMORY_SCOPE_AGENT);
}

// one-hop all-to-all barrier: WG i stores flags[i]; thread tid polls WG tid's
// flag (one vector coherent load per wave per poll round). 2 MALL latencies.
// Full-join semantics: no WG proceeds until all 256 flags reach ep.
__device__ __forceinline__ void gridbar(unsigned* flags, unsigned ep, int wg, int tid){
  asm volatile("s_waitcnt vmcnt(0)" ::: "memory");  // sc1 h-stores at MALL
  __syncthreads();                                  // whole WG drained
  if (tid == 0) stflag(&flags[wg*16], ep);
  while (ldflag(&flags[tid*16]) < ep) __builtin_amdgcn_s_sleep(1);
  __syncthreads();                                  // all 256 flags confirmed
}

// x [B,T,D] fp32 -> X8 bf16 in [T][D/8][B][8]
__global__ void xpose_kernel(const float* __restrict__ x, unsigned short* __restrict__ X8){
  int idx   = blockIdx.x*256 + threadIdx.x;
  int t     = idx >> 11;
  int rem   = idx & 2047;
  int plane = rem >> 6;
  int b     = rem & 63;
  const float* src = x + ((size_t)b << 18) + (t << 8) + (plane << 3);
  unsigned short tmp[8];
  #pragma unroll
  for (int j = 0; j < 8; ++j) tmp[j] = f2bf(src[j]);
  int4 v; __builtin_memcpy(&v, tmp, 16);
  ((int4*)X8)[idx] = v;
}

// H0C/H1C: true = coherent sc0 loads (double-buffer tier), false = plain loads
// (history tier: fresh address per step -> XCD-local L2 sharing is safe).
template<bool H0C, bool H1C>
__global__ void __launch_bounds__(TPB, 1)
lstm_mega(const float* __restrict__ Wih0, const float* __restrict__ Whh0,
          const float* __restrict__ bih0, const float* __restrict__ bhh0,
          const float* __restrict__ Wih1, const float* __restrict__ Whh1,
          const float* __restrict__ bih1, const float* __restrict__ bhh1,
          const unsigned short* __restrict__ X8,
          unsigned* flags, unsigned* gen,
          u64* H0, u64* H1, int d0, int d1,
          float* __restrict__ out)
{
  extern __shared__ unsigned short Ws[];   // [32][KP]
  const int tid   = threadIdx.x;
  const int wg    = blockIdx.x;
  const int layer = (wg >= NL0);
  const int wgl   = layer ? wg - NL0 : wg;
  const int KD    = layer ? K1  : K0;
  const int dlen  = layer ? HD  : DIN;
  const int KP    = layer ? K1P : K0P;
  const int4* X4  = (const int4*)X8;

  // ---- stage this WG's 32 gate-rows (8 cols x 4 gates) into LDS (bf16) ----
  {
    const float* Wih = layer ? Wih1 : Wih0;
    const float* Whh = layer ? Whh1 : Whh0;
    for (int m = 0; m < 32; ++m){
      int gr = (m & 3)*HD + wgl*8 + (m >> 2);      // gate-major global row
      const float* ar = Wih + (size_t)gr*dlen;
      const float* br = Whh + (size_t)gr*HD;
      unsigned short* row = Ws + m*KP;
      for (int k = tid; k < KD; k += TPB)
        row[k] = f2bf(k < dlen ? ar[k] : br[k - dlen]);
    }
  }
  __syncthreads();

  const int lane  = tid & 63;
  const int wv    = tid >> 6;
  const int q     = lane >> 4;       // k-quad (A/B frags); row-quad (C/D)
  const int nn    = lane & 15;       // A-row / B-batch / C-batch
  const int batch = wv*16 + nn;

  float bias[2][4];
  {
    const float* bi = layer ? bih1 : bih0;
    const float* bh = layer ? bhh1 : bhh0;
    #pragma unroll
    for (int rt = 0; rt < 2; ++rt){
      int colr = wgl*8 + rt*4 + q;
      #pragma unroll
      for (int r = 0; r < 4; ++r)
        bias[rt][r] = bi[r*HD + colr] + bh[r*HD + colr];
    }
  }

  float cst[2] = {0.f, 0.f};
  float hv[2]  = {0.f, 0.f};

  auto do_step = [&](int t){
    f32x4 a00 = {0,0,0,0}, a01 = {0,0,0,0}, a10 = {0,0,0,0}, a11 = {0,0,0,0};

    auto MM = [&](int kb, bf16x8 b){
      bf16x8 a0, a1;
      __builtin_memcpy(&a0, &Ws[nn*KP + kb*32 + q*8], 16);
      __builtin_memcpy(&a1, &Ws[(16+nn)*KP + kb*32 + q*8], 16);
      if (kb & 1){ a01 = __builtin_amdgcn_mfma_f32_16x16x32_bf16(a0,b,a01,0,0,0);
                   a11 = __builtin_amdgcn_mfma_f32_16x16x32_bf16(a1,b,a11,0,0,0); }
      else       { a00 = __builtin_amdgcn_mfma_f32_16x16x32_bf16(a0,b,a00,0,0,0);
                   a10 = __builtin_amdgcn_mfma_f32_16x16x32_bf16(a1,b,a10,0,0,0); }
    };

    if (!layer){
      // ---- layer 0: gates = W0 @ [x_t ; h0(t-1)] ----
      const int4* xb = X4 + (size_t)t*2048;
      const u64* hb  = H0 + (size_t)(t % d0)*HSLAB_U64;     // h0(t-1) slot

      int4 xr[8];
      #pragma unroll
      for (int kb = 0; kb < 8; ++kb)            // x part: L2-cached
        xr[kb] = xb[(kb*4 + q)*64 + batch];

      u64 B[3][16];                             // 8 kb-planes per chunk, depth-3
      auto LD = [&](int c){                     // chunk c: h-planes c*8 .. c*8+7
        u64* d = B[c % 3];
        #pragma unroll
        for (int i = 0; i < 8; ++i){
          const u64* p = hb + (((c*8 + i)*4 + q)*64 + batch)*2;
          d[2*i]   = H0C ? ld64c(p)     : p[0];
          d[2*i+1] = H0C ? ld64c(p + 1) : p[1];
        }
      };
      LD(0); LD(1);
      #pragma unroll
      for (int kb = 0; kb < 8; ++kb){
        bf16x8 b; __builtin_memcpy(&b, &xr[kb], 16);
        MM(kb, b);
      }
      LD(2);
      #pragma unroll
      for (int c = 0; c < 4; ++c){
        u64* d = B[c % 3];
        #pragma unroll
        for (int i = 0; i < 8; ++i){
          u64 pair[2] = {d[2*i], d[2*i+1]};
          bf16x8 b; __builtin_memcpy(&b, pair, 16);
          MM(8 + c*8 + i, b);
        }
        if (c + 3 < 4) LD(c + 3);
      }
    } else {
      // ---- layer 1: gates = W1 @ [y0(t) ; h1(t-1)] ----
      const u64* yb = H0 + (size_t)((t+1) % d0)*HSLAB_U64;  // y0(t) slot
      const u64* hb = H1 + (size_t)(t % d1)*HSLAB_U64;      // h1(t-1) slot

      u64 B[3][16];                              // 8 chunks of 8 kb, depth-3
      auto LD = [&](int c){                      // c<4 from yb, else from hb
        const u64* src = (c < 4) ? yb : hb;
        int p0 = (c & 3)*8;
        u64* d = B[c % 3];
        #pragma unroll
        for (int i = 0; i < 8; ++i){
          const u64* p = src + (((p0 + i)*4 + q)*64 + batch)*2;
          if (c < 4){ d[2*i] = H0C ? ld64c(p) : p[0];
                      d[2*i+1] = H0C ? ld64c(p + 1) : p[1]; }
          else      { d[2*i] = H1C ? ld64c(p) : p[0];
                      d[2*i+1] = H1C ? ld64c(p + 1) : p[1]; }
        }
      };
      LD(0); LD(1); LD(2);
      #pragma unroll
      for (int c = 0; c < 8; ++c){
        u64* d = B[c % 3];
        #pragma unroll
        for (int i = 0; i < 8; ++i){
          u64 pair[2] = {d[2*i], d[2*i+1]};
          bf16x8 b; __builtin_memcpy(&b, pair, 16);
          MM(c*8 + i, b);
        }
        if (c + 3 < 8) LD(c + 3);
      }
    }

    f32x4 s0 = a00 + a01, s1 = a10 + a11;
    u64* Hw = layer ? H1 : H0;
    int  wd = layer ? d1 : d0;
    unsigned short* wbase = (unsigned short*)(Hw + (size_t)((t+1) % wd)*HSLAB_U64);
    #pragma unroll
    for (int rt = 0; rt < 2; ++rt){
      f32x4 s = rt ? s1 : s0;
      float ii = sigmf(s[0] + bias[rt][0]);
      float ff = sigmf(s[1] + bias[rt][1]);
      float gg = tanhf_fast(s[2] + bias[rt][2]);
      float oo = sigmf(s[3] + bias[rt][3]);
      cst[rt] = ff*cst[rt] + ii*gg;
      hv[rt]  = oo*tanhf_fast(cst[rt]);
      st16c(wbase + (wgl*64 + batch)*8 + (rt*4 + q), f2bf(hv[rt]));
    }
  };

  if (!layer){
    for (int s = 0; s < T_STEPS; ++s){
      do_step(s);
      gridbar(flags, (unsigned)(s+1), wg, tid);
    }
  } else {
    for (int s = 0; s < T_STEPS; ++s){
      if (s > 0) do_step(s-1);
      gridbar(flags, (unsigned)(s+1), wg, tid);
    }
    do_step(T_STEPS-1);
  }

  // out = [h0 | h1 | c0 | c1], each [B=64, H=1024] fp32
  {
    int col0 = wgl*8 + q;
    int base = layer ? 65536 : 0;
    out[base          + batch*HD + col0    ] = hv[0];
    out[base          + batch*HD + col0 + 4] = hv[1];
    out[base + 131072 + batch*HD + col0    ] = cst[0];
    out[base + 131072 + batch*HD + col0 + 4] = cst[1];
  }
}

extern "C" void kernel_launch(void* const* d_in, const int* in_sizes, int n_in,
                              void* d_out, int out_size, void* d_ws, size_t ws_size,
                              hipStream_t stream)
{
  const float* x    = (const float*)d_in[0];
  const float* Wih0 = (const float*)d_in[1];
  const float* Whh0 = (const float*)d_in[2];
  const float* bih0 = (const float*)d_in[3];
  const float* bhh0 = (const float*)d_in[4];
  const float* Wih1 = (const float*)d_in[5];
  const float* Whh1 = (const float*)d_in[6];
  const float* bih1 = (const float*)d_in[7];
  const float* bhh1 = (const float*)d_in[8];
  float* out = (float*)d_out;

  char* ws = (char*)d_ws;
  unsigned* flags = (unsigned*)ws;
  unsigned* gen   = (unsigned*)(ws + 16384);

  const size_t need2 = FLAGS_BYTES + 2*HIST_BYTES + X8_BYTES;               // ~302 MB
  const size_t need1 = FLAGS_BYTES + HIST_BYTES + 2*HSLAB_BYTES + X8_BYTES; // ~168 MB

  u64 *H0p, *H1p; unsigned short* X8p; int d0, d1, tier;
  if (ws_size >= need2){
    tier = 2; d0 = HIST_DEPTH; d1 = HIST_DEPTH;
    H0p = (u64*)(ws + FLAGS_BYTES);
    H1p = (u64*)(ws + FLAGS_BYTES + HIST_BYTES);
    X8p = (unsigned short*)(ws + FLAGS_BYTES + 2*HIST_BYTES);
  } else if (ws_size >= need1){
    tier = 1; d0 = HIST_DEPTH; d1 = 2;
    H0p = (u64*)(ws + FLAGS_BYTES);
    H1p = (u64*)(ws + FLAGS_BYTES + HIST_BYTES);
    X8p = (unsigned short*)(ws + FLAGS_BYTES + HIST_BYTES + 2*HSLAB_BYTES);
  } else {
    tier = 0; d0 = 2; d1 = 2;
    H0p = (u64*)(ws + FLAGS_BYTES);
    H1p = (u64*)(ws + FLAGS_BYTES + 2*HSLAB_BYTES);
    X8p = (unsigned short*)(ws + FLAGS_BYTES + 4*HSLAB_BYTES);
  }

  // zero flags + slot 0 of each h buffer (initial state h(-1)=0)
  hipMemsetAsync(flags, 0, FLAGS_BYTES, stream);
  hipMemsetAsync(H0p, 0, HSLAB_BYTES, stream);
  hipMemsetAsync(H1p, 0, HSLAB_BYTES, stream);
  xpose_kernel<<<8192, 256, 0, stream>>>(x, X8p);

  void* fn = (tier == 2) ? (void*)&lstm_mega<false,false>
           : (tier == 1) ? (void*)&lstm_mega<false,true>
                         : (void*)&lstm_mega<true,true>;
  hipFuncSetAttribute(fn, hipFuncAttributeMaxDynamicSharedMemorySize, SMEM_BYTES);

  const unsigned short* X8c = X8p;
  void* args[] = {(void*)&Wih0,(void*)&Whh0,(void*)&bih0,(void*)&bhh0,
                  (void*)&Wih1,(void*)&Whh1,(void*)&bih1,(void*)&bhh1,
                  (void*)&X8c,(void*)&flags,(void*)&gen,
                  (void*)&H0p,(void*)&H1p,(void*)&d0,(void*)&d1,(void*)&out};
  hipError_t err = hipLaunchCooperativeKernel(fn, dim3(NWG), dim3(TPB),
                                              args, SMEM_BYTES, stream);
  if (err != hipSuccess){
    // Fallback: plain launch. 256 WGs x 131.6KB LDS => 1 WG/CU, grid == CU
    // count, all WGs co-resident by capacity.
    if (tier == 2)
      lstm_mega<false,false><<<dim3(NWG), dim3(TPB), SMEM_BYTES, stream>>>(
        Wih0,Whh0,bih0,bhh0,Wih1,Whh1,bih1,bhh1,X8c,flags,gen,H0p,H1p,d0,d1,out);
    else if (tier == 1)
      lstm_mega<false,true><<<dim3(NWG), dim3(TPB), SMEM_BYTES, stream>>>(
        Wih0,Whh0,bih0,bhh0,Wih1,Whh1,bih1,bhh1,X8c,flags,gen,H0p,H1p,d0,d1,out);
    else
      lstm_mega<true,true><<<dim3(NWG), dim3(TPB), SMEM_BYTES, stream>>>(
        Wih0,Whh0,bih0,bhh0,Wih1,Whh1,bih1,bhh1,X8c,flags,gen,H0p,H1p,d0,d1,out);
  }
}